// Round 1
// baseline (384.576 us; speedup 1.0000x reference)
//
#include <hip/hip_runtime.h>
#include <math.h>

#define BB 32
#define SS 2048
#define EE 128
#define NH 8
#define HDIM 16
#define CACHE_LEN 256
#define SINKS 4
#define WINDOW 128
#define KSEL (SINKS + WINDOW)   // 132
#define ROWS (BB * SS)          // 65536

// workspace layout (bytes)
#define WS_MAXX 0                         // uint bits of max|x|
#define WS_MAXO 4                         // uint bits of max|attn_out|
#define WS_WS   16                        // float[4] w_scales (q,k,v,o)
#define WS_W(i) (256 + (i) * 16384)       // packed ternary int8, [e/4][o][e%4]
#define WS_QBUF (256 + 4 * 16384)         // 65792: q rows (ROWS x 128 f32)
#define WS_KBUF (WS_QBUF + (size_t)ROWS * EE * 4)
#define WS_VBUF (WS_KBUF + (size_t)BB * WINDOW * EE * 4)
// total ws need: ~37.8 MB (attn_out lives in d_out in-place)

__global__ void prep_weights(const float* __restrict__ qw, const float* __restrict__ kw,
                             const float* __restrict__ vw, const float* __restrict__ ow,
                             char* __restrict__ ws) {
    const float* W[4] = {qw, kw, vw, ow};
    const int m = blockIdx.x;
    const float* w = W[m];
    __shared__ double red[256];
    const int tid = threadIdx.x;
    double s = 0.0;
    for (int j = tid; j < 16384; j += 256) s += fabs((double)w[j]);
    red[tid] = s;
    __syncthreads();
    for (int st = 128; st > 0; st >>= 1) {
        if (tid < st) red[tid] += red[tid + st];
        __syncthreads();
    }
    const double wscale = red[0] / 16384.0;
    const double thr = 0.5 * wscale;
    if (tid == 0) {
        ((float*)(ws + WS_WS))[m] = (float)wscale;
        if (m == 0) {
            *(unsigned*)(ws + WS_MAXX) = 0u;
            *(unsigned*)(ws + WS_MAXO) = 0u;
        }
    }
    signed char* tw = (signed char*)(ws + WS_W(m));
    for (int j = tid; j < 16384; j += 256) {
        const int o = j >> 7, e = j & 127;
        const float wv = w[j];
        const double av = fabs((double)wv);
        const signed char t = (av > thr) ? (wv > 0.f ? (signed char)1 : (signed char)-1) : (signed char)0;
        tw[((e >> 2) << 9) + (o << 2) + (e & 3)] = t;
    }
}

__global__ void reduce_max_x(const float* __restrict__ x, char* __restrict__ ws) {
    __shared__ float red[256];
    const int tid = threadIdx.x;
    float mx = 0.f;
    const int n4 = ROWS * EE / 4;
    for (int i = blockIdx.x * blockDim.x + tid; i < n4; i += gridDim.x * blockDim.x) {
        const float4 v = ((const float4*)x)[i];
        mx = fmaxf(mx, fmaxf(fmaxf(fabsf(v.x), fabsf(v.y)), fmaxf(fabsf(v.z), fabsf(v.w))));
    }
    red[tid] = mx;
    __syncthreads();
    for (int st = 128; st > 0; st >>= 1) {
        if (tid < st) red[tid] = fmaxf(red[tid], red[tid + st]);
        __syncthreads();
    }
    if (tid == 0) atomicMax((unsigned*)(ws + WS_MAXX), __float_as_uint(red[0]));
}

__device__ __forceinline__ float tern_dot(const signed char* __restrict__ tw,
                                          const float* __restrict__ qx, int t) {
    float acc = 0.f;
#pragma unroll
    for (int e4 = 0; e4 < 32; ++e4) {
        const char4 wv = *(const char4*)(tw + e4 * 512 + t * 4);
        const float4 xq = *(const float4*)(qx + e4 * 4);
        acc = fmaf(xq.x, (float)wv.x, acc);
        acc = fmaf(xq.y, (float)wv.y, acc);
        acc = fmaf(xq.z, (float)wv.z, acc);
        acc = fmaf(xq.w, (float)wv.w, acc);
    }
    return acc;
}

__global__ __launch_bounds__(128) void qkv_proj(const float* __restrict__ x,
                                                const float* __restrict__ qb,
                                                const float* __restrict__ kb,
                                                const float* __restrict__ vb,
                                                char* __restrict__ ws) {
    const int r = blockIdx.x;
    const int t = threadIdx.x;
    const int b = r >> 11, s = r & 2047;
    __shared__ __align__(16) float qx[128];
    const float maxx = __uint_as_float(*(const unsigned*)(ws + WS_MAXX));
    const float iscale = maxx / 127.0f;
    const float xi = x[(size_t)r * 128 + t];
    float qv = rintf(xi / iscale);
    qv = fminf(fmaxf(qv, -128.f), 127.f);
    qx[t] = qv;
    __syncthreads();
    const float* wsc = (const float*)(ws + WS_WS);
    {
        const float acc = tern_dot((const signed char*)(ws + WS_W(0)), qx, t);
        ((float*)(ws + WS_QBUF))[(size_t)r * 128 + t] = acc * (wsc[0] * iscale) + qb[t];
    }
    if (s >= SS - WINDOW) {
        const int kr = b * WINDOW + (s - (SS - WINDOW));
        {
            const float acc = tern_dot((const signed char*)(ws + WS_W(1)), qx, t);
            ((float*)(ws + WS_KBUF))[(size_t)kr * 128 + t] = acc * (wsc[1] * iscale) + kb[t];
        }
        {
            const float acc = tern_dot((const signed char*)(ws + WS_W(2)), qx, t);
            ((float*)(ws + WS_VBUF))[(size_t)kr * 128 + t] = acc * (wsc[2] * iscale) + vb[t];
        }
    }
}

// one thread per query; K/V selected tiles in LDS; online softmax.
// attention output written to d_out[0 .. ROWS*128) (later overwritten in-place by o_proj)
__global__ __launch_bounds__(256) void attention(const float* __restrict__ ck,
                                                 const float* __restrict__ cv,
                                                 char* __restrict__ ws,
                                                 float* __restrict__ aout) {
    const int qt = blockIdx.x, h = blockIdx.y, b = blockIdx.z;
    __shared__ __align__(16) float ksh[KSEL * 16];
    __shared__ __align__(16) float vsh[KSEL * 16];
    __shared__ float red[256];
    const int tid = threadIdx.x;
    const float* kbuf = (const float*)(ws + WS_KBUF);
    const float* vbuf = (const float*)(ws + WS_VBUF);
    for (int idx = tid; idx < KSEL * 16; idx += 256) {
        const int j = idx >> 4, d = idx & 15;
        float kv, vv;
        if (j < SINKS) {
            kv = ck[((size_t)(b * NH + h) * CACHE_LEN + j) * 16 + d];
            vv = cv[((size_t)(b * NH + h) * CACHE_LEN + j) * 16 + d];
        } else {
            kv = kbuf[(size_t)(b * WINDOW + (j - SINKS)) * 128 + h * 16 + d];
            vv = vbuf[(size_t)(b * WINDOW + (j - SINKS)) * 128 + h * 16 + d];
        }
        ksh[idx] = kv;
        vsh[idx] = vv;
    }
    __syncthreads();
    const int qi = qt * 256 + tid;
    const float* qrow = (const float*)(ws + WS_QBUF) + (size_t)(b * SS + qi) * 128 + h * 16;
    float q[16];
#pragma unroll
    for (int i = 0; i < 4; ++i) {
        const float4 v = ((const float4*)qrow)[i];
        q[i * 4 + 0] = v.x; q[i * 4 + 1] = v.y; q[i * 4 + 2] = v.z; q[i * 4 + 3] = v.w;
    }
    const int jmax = (qi < KSEL - 1) ? qi : (KSEL - 1);
    float m = -INFINITY, l = 0.f;
    float o[16];
#pragma unroll
    for (int d = 0; d < 16; ++d) o[d] = 0.f;
    for (int j = 0; j <= jmax; ++j) {
        float s = 0.f;
#pragma unroll
        for (int d = 0; d < 16; ++d) s = fmaf(q[d], ksh[j * 16 + d], s);
        s *= 0.25f;  // 1/sqrt(16)
        const float mn = fmaxf(m, s);
        const float cs = __expf(m - mn);   // first iter: exp(-inf)=0
        const float p = __expf(s - mn);
        l = l * cs + p;
#pragma unroll
        for (int d = 0; d < 16; ++d) o[d] = fmaf(o[d], cs, p * vsh[j * 16 + d]);
        m = mn;
    }
    const float inv = 1.0f / l;
    float tm = 0.f;
    float* ao = aout + (size_t)(b * SS + qi) * 128 + h * 16;
#pragma unroll
    for (int i = 0; i < 4; ++i) {
        float4 v;
        v.x = o[i * 4 + 0] * inv;
        v.y = o[i * 4 + 1] * inv;
        v.z = o[i * 4 + 2] * inv;
        v.w = o[i * 4 + 3] * inv;
        tm = fmaxf(tm, fmaxf(fmaxf(fabsf(v.x), fabsf(v.y)), fmaxf(fabsf(v.z), fabsf(v.w))));
        ((float4*)ao)[i] = v;
    }
    red[tid] = tm;
    __syncthreads();
    for (int st = 128; st > 0; st >>= 1) {
        if (tid < st) red[tid] = fmaxf(red[tid], red[tid + st]);
        __syncthreads();
    }
    if (tid == 0) atomicMax((unsigned*)(ws + WS_MAXO), __float_as_uint(red[0]));
}

// in-place: block r reads out[r,:] (attention output), writes out[r,:] (projected)
__global__ __launch_bounds__(128) void o_proj(const float* __restrict__ ob,
                                              char* __restrict__ ws,
                                              float* __restrict__ out) {
    const int r = blockIdx.x;
    const int t = threadIdx.x;
    __shared__ __align__(16) float qx[128];
    const float maxo = __uint_as_float(*(const unsigned*)(ws + WS_MAXO));
    const float iscale = maxo / 127.0f;
    const float xi = out[(size_t)r * 128 + t];
    float qv = rintf(xi / iscale);
    qx[t] = fminf(fmaxf(qv, -128.f), 127.f);
    __syncthreads();
    const float acc = tern_dot((const signed char*)(ws + WS_W(3)), qx, t);
    const float wsc = ((const float*)(ws + WS_WS))[3];
    out[(size_t)r * 128 + t] = acc * (wsc * iscale) + ob[t];
}

__global__ void copy_newkv(const char* __restrict__ ws, float* __restrict__ out) {
    const int n = BB * NH * WINDOW * 16;  // 524288
    const float* kbuf = (const float*)(ws + WS_KBUF);
    const float* vbuf = (const float*)(ws + WS_VBUF);
    float* nk = out + (size_t)ROWS * EE;
    float* nv = nk + n;
    for (int i = blockIdx.x * blockDim.x + threadIdx.x; i < n; i += gridDim.x * blockDim.x) {
        const int d = i & 15, p = (i >> 4) & 127, h = (i >> 11) & 7, b = i >> 14;
        const size_t src = (size_t)(b * WINDOW + p) * 128 + h * 16 + d;
        nk[i] = kbuf[src];
        nv[i] = vbuf[src];
    }
}

extern "C" void kernel_launch(void* const* d_in, const int* in_sizes, int n_in,
                              void* d_out, int out_size, void* d_ws, size_t ws_size,
                              hipStream_t stream) {
    const float* x  = (const float*)d_in[0];
    const float* ck = (const float*)d_in[1];
    const float* cv = (const float*)d_in[2];
    const float* qw = (const float*)d_in[3];
    const float* qb = (const float*)d_in[4];
    const float* kw = (const float*)d_in[5];
    const float* kb = (const float*)d_in[6];
    const float* vw = (const float*)d_in[7];
    const float* vb = (const float*)d_in[8];
    const float* ow = (const float*)d_in[9];
    const float* ob = (const float*)d_in[10];
    char* ws = (char*)d_ws;
    float* out = (float*)d_out;

    prep_weights<<<4, 256, 0, stream>>>(qw, kw, vw, ow, ws);
    reduce_max_x<<<1024, 256, 0, stream>>>(x, ws);
    qkv_proj<<<ROWS, 128, 0, stream>>>(x, qb, kb, vb, ws);
    attention<<<dim3(SS / 256, NH, BB), 256, 0, stream>>>(ck, cv, ws, out);
    copy_newkv<<<512, 256, 0, stream>>>(ws, out);
    o_proj<<<ROWS, 128, 0, stream>>>(ob, ws, out);
}

// Round 2
// 255.788 us; speedup vs baseline: 1.5035x; 1.5035x over previous
//
#include <hip/hip_runtime.h>
#include <math.h>

#define BB 32
#define SS 2048
#define EE 128
#define NH 8
#define HDIM 16
#define CACHE_LEN 256
#define SINKS 4
#define WINDOW 128
#define KSEL (SINKS + WINDOW)   // 132
#define ROWS (BB * SS)          // 65536

typedef int v4i __attribute__((ext_vector_type(4)));

// workspace layout (bytes)
#define WS_MAXX 0                         // uint bits of max|x|
#define WS_MAXO 4                         // uint bits of max|attn_out|
#define WS_WS   16                        // float[4] w_scales (q,k,v,o)
#define WS_W(i) (256 + (i) * 16384)       // ternary int8, row-major [o][e]
#define WS_QBUF (256 + 4 * 16384)         // q rows (ROWS x 128 f32)
#define WS_KBUF (WS_QBUF + (size_t)ROWS * EE * 4)
#define WS_VBUF (WS_KBUF + (size_t)BB * WINDOW * EE * 4)

__global__ void prep_weights(const float* __restrict__ qw, const float* __restrict__ kw,
                             const float* __restrict__ vw, const float* __restrict__ ow,
                             char* __restrict__ ws) {
    const float* W[4] = {qw, kw, vw, ow};
    const int m = blockIdx.x;
    const float* w = W[m];
    __shared__ double red[256];
    const int tid = threadIdx.x;
    double s = 0.0;
    for (int j = tid; j < 16384; j += 256) s += fabs((double)w[j]);
    red[tid] = s;
    __syncthreads();
    for (int st = 128; st > 0; st >>= 1) {
        if (tid < st) red[tid] += red[tid + st];
        __syncthreads();
    }
    const double wscale = red[0] / 16384.0;
    const double thr = 0.5 * wscale;
    if (tid == 0) {
        ((float*)(ws + WS_WS))[m] = (float)wscale;
        if (m == 0) {
            *(unsigned*)(ws + WS_MAXX) = 0u;
            *(unsigned*)(ws + WS_MAXO) = 0u;
        }
    }
    signed char* tw = (signed char*)(ws + WS_W(m));
    for (int j = tid; j < 16384; j += 256) {
        const float wv = w[j];
        const double av = fabs((double)wv);
        tw[j] = (av > thr) ? (wv > 0.f ? (signed char)1 : (signed char)-1) : (signed char)0;
    }
}

__global__ void reduce_max_x(const float* __restrict__ x, char* __restrict__ ws) {
    __shared__ float red[256];
    const int tid = threadIdx.x;
    float mx = 0.f;
    const int n4 = ROWS * EE / 4;
    for (int i = blockIdx.x * blockDim.x + tid; i < n4; i += gridDim.x * blockDim.x) {
        const float4 v = ((const float4*)x)[i];
        mx = fmaxf(mx, fmaxf(fmaxf(fabsf(v.x), fabsf(v.y)), fmaxf(fabsf(v.z), fabsf(v.w))));
    }
    red[tid] = mx;
    __syncthreads();
    for (int st = 128; st > 0; st >>= 1) {
        if (tid < st) red[tid] = fmaxf(red[tid], red[tid + st]);
        __syncthreads();
    }
    if (tid == 0) atomicMax((unsigned*)(ws + WS_MAXX), __float_as_uint(red[0]));
}

// ---- int8 MFMA projection ----------------------------------------------
// One block = 256 thr = 4 waves; each wave computes a 16-row x 128-col tile.
// A: int8 activations staged in LDS (row stride 144B). B: ternary weights,
// per-lane fragments in registers (16 x v4i = 64 VGPR).
// proj: 0=Q(all rows), 1=K(window), 2=V(window)
__global__ __launch_bounds__(256) void qkv_proj_mfma(const float* __restrict__ x,
                                                     const float* __restrict__ qb,
                                                     const float* __restrict__ kb,
                                                     const float* __restrict__ vb,
                                                     char* __restrict__ ws) {
    const int bx = blockIdx.x;
    const int tid = threadIdx.x;
    int proj, in_row0, out_row0;
    if (bx < 1024) {
        proj = 0; in_row0 = bx * 64; out_row0 = bx * 64;
    } else {
        int widx = bx - 1024;
        proj = 1 + (widx >> 6);
        widx &= 63;
        in_row0 = (widx >> 1) * 2048 + (SS - WINDOW) + (widx & 1) * 64;
        out_row0 = widx * 64;
    }
    const float* bias = (proj == 0) ? qb : (proj == 1) ? kb : vb;
    float* outbuf = (proj == 0) ? (float*)(ws + WS_QBUF)
                  : (proj == 1) ? (float*)(ws + WS_KBUF)
                                : (float*)(ws + WS_VBUF);
    const signed char* tw = (const signed char*)(ws + WS_W(proj));

    const int lane = tid & 63;
    const int wv = tid >> 6;       // wave id 0..3 -> row tile
    const int ml = lane & 15;      // m / n within tile
    const int quad = lane >> 4;    // 0..3

    // B fragments: coltile c (0..7), kstep s (0..1)
    v4i bfrag[8][2];
#pragma unroll
    for (int c = 0; c < 8; ++c)
#pragma unroll
        for (int s = 0; s < 2; ++s)
            bfrag[c][s] = *(const v4i*)(tw + (c * 16 + ml) * 128 + s * 64 + quad * 16);

    // stage + quantize x: 64 rows x 128 int8, LDS stride 144
    __shared__ __align__(16) signed char lds_a[64 * 144];
    const float maxx = __uint_as_float(*(const unsigned*)(ws + WS_MAXX));
    const float iscale = maxx / 127.0f;
    const float4* x4 = (const float4*)(x + (size_t)in_row0 * 128);
#pragma unroll
    for (int it = 0; it < 8; ++it) {
        const int i = tid + it * 256;       // 0..2047
        const int row = i >> 5, c4 = i & 31;
        const float4 v = x4[i];
        float a0 = fminf(fmaxf(rintf(v.x / iscale), -128.f), 127.f);
        float a1 = fminf(fmaxf(rintf(v.y / iscale), -128.f), 127.f);
        float a2 = fminf(fmaxf(rintf(v.z / iscale), -128.f), 127.f);
        float a3 = fminf(fmaxf(rintf(v.w / iscale), -128.f), 127.f);
        const int i0 = (int)a0, i1 = (int)a1, i2 = (int)a2, i3 = (int)a3;
        const int packed = (i0 & 0xff) | ((i1 & 0xff) << 8) | ((i2 & 0xff) << 16) | (i3 << 24);
        *(int*)(lds_a + row * 144 + c4 * 4) = packed;
    }
    __syncthreads();

    // A fragments for this wave's 16-row tile
    const v4i afrag0 = *(const v4i*)(lds_a + (wv * 16 + ml) * 144 + quad * 16);
    const v4i afrag1 = *(const v4i*)(lds_a + (wv * 16 + ml) * 144 + 64 + quad * 16);

    const float wsc = ((const float*)(ws + WS_WS))[proj];
    const float scale = wsc * iscale;

#pragma unroll
    for (int c = 0; c < 8; ++c) {
        v4i acc = {0, 0, 0, 0};
        acc = __builtin_amdgcn_mfma_i32_16x16x64_i8(afrag0, bfrag[c][0], acc, 0, 0, 0);
        acc = __builtin_amdgcn_mfma_i32_16x16x64_i8(afrag1, bfrag[c][1], acc, 0, 0, 0);
        const int col = c * 16 + ml;
        const float bcol = bias[col];
#pragma unroll
        for (int r = 0; r < 4; ++r) {
            const int row = wv * 16 + quad * 4 + r;
            outbuf[(size_t)(out_row0 + row) * 128 + col] = (float)acc[r] * scale + bcol;
        }
    }
}

// ---- attention: one thread per query, chunked online softmax -----------
__global__ __launch_bounds__(256) void attention(const float* __restrict__ ck,
                                                 const float* __restrict__ cv,
                                                 char* __restrict__ ws,
                                                 float* __restrict__ aout) {
    const int qt = blockIdx.x, h = blockIdx.y, b = blockIdx.z;
    __shared__ __align__(16) float ksh[KSEL * 16];
    __shared__ __align__(16) float vsh[KSEL * 16];
    __shared__ float red[256];
    const int tid = threadIdx.x;
    const float* kbuf = (const float*)(ws + WS_KBUF);
    const float* vbuf = (const float*)(ws + WS_VBUF);
    for (int idx = tid; idx < KSEL * 16; idx += 256) {
        const int j = idx >> 4, d = idx & 15;
        float kv, vv;
        if (j < SINKS) {
            kv = ck[((size_t)(b * NH + h) * CACHE_LEN + j) * 16 + d];
            vv = cv[((size_t)(b * NH + h) * CACHE_LEN + j) * 16 + d];
        } else {
            kv = kbuf[(size_t)(b * WINDOW + (j - SINKS)) * 128 + h * 16 + d];
            vv = vbuf[(size_t)(b * WINDOW + (j - SINKS)) * 128 + h * 16 + d];
        }
        ksh[idx] = kv;
        vsh[idx] = vv;
    }
    __syncthreads();
    const int qi = qt * 256 + tid;
    const float* qrow = (const float*)(ws + WS_QBUF) + (size_t)(b * SS + qi) * 128 + h * 16;
    float q[16];
#pragma unroll
    for (int i = 0; i < 4; ++i) {
        const float4 v = ((const float4*)qrow)[i];
        q[i * 4 + 0] = v.x; q[i * 4 + 1] = v.y; q[i * 4 + 2] = v.z; q[i * 4 + 3] = v.w;
    }
    const int jmax = (qi < KSEL - 1) ? qi : (KSEL - 1);
    float m = -INFINITY, l = 0.f;
    float o[16];
#pragma unroll
    for (int d = 0; d < 16; ++d) o[d] = 0.f;

#pragma unroll
    for (int ch = 0; ch < 4; ++ch) {
        const int j0 = ch * 33;
        float sc[33];
        float mc = -INFINITY;
#pragma unroll
        for (int i = 0; i < 33; ++i) {
            const int j = j0 + i;
            float s = 0.f;
#pragma unroll
            for (int d = 0; d < 16; ++d) s = fmaf(q[d], ksh[j * 16 + d], s);
            s *= 0.25f;  // 1/sqrt(16)
            s = (j <= jmax) ? s : -INFINITY;
            sc[i] = s;
            mc = fmaxf(mc, s);
        }
        const float mn = fmaxf(m, mc);
        const float cs = __expf(m - mn);   // chunk 0: exp(-inf)=0
        l *= cs;
#pragma unroll
        for (int d = 0; d < 16; ++d) o[d] *= cs;
#pragma unroll
        for (int i = 0; i < 33; ++i) {
            const float p = __expf(sc[i] - mn);
            l += p;
            const int j = j0 + i;
#pragma unroll
            for (int d = 0; d < 16; ++d) o[d] = fmaf(p, vsh[j * 16 + d], o[d]);
        }
        m = mn;
    }

    const float inv = 1.0f / l;
    float tm = 0.f;
    float* ao = aout + (size_t)(b * SS + qi) * 128 + h * 16;
#pragma unroll
    for (int i = 0; i < 4; ++i) {
        float4 v;
        v.x = o[i * 4 + 0] * inv;
        v.y = o[i * 4 + 1] * inv;
        v.z = o[i * 4 + 2] * inv;
        v.w = o[i * 4 + 3] * inv;
        tm = fmaxf(tm, fmaxf(fmaxf(fabsf(v.x), fabsf(v.y)), fmaxf(fabsf(v.z), fabsf(v.w))));
        ((float4*)ao)[i] = v;
    }
    red[tid] = tm;
    __syncthreads();
    for (int st = 128; st > 0; st >>= 1) {
        if (tid < st) red[tid] = fmaxf(red[tid], red[tid + st]);
        __syncthreads();
    }
    if (tid == 0) atomicMax((unsigned*)(ws + WS_MAXO), __float_as_uint(red[0]));
}

// ---- O projection, int8 MFMA, in-place on d_out ------------------------
__global__ __launch_bounds__(256) void o_proj_mfma(const float* __restrict__ ob,
                                                   char* __restrict__ ws,
                                                   float* __restrict__ out) {
    const int bx = blockIdx.x;
    const int tid = threadIdx.x;
    const int in_row0 = bx * 64;
    const signed char* tw = (const signed char*)(ws + WS_W(3));

    const int lane = tid & 63;
    const int wv = tid >> 6;
    const int ml = lane & 15;
    const int quad = lane >> 4;

    v4i bfrag[8][2];
#pragma unroll
    for (int c = 0; c < 8; ++c)
#pragma unroll
        for (int s = 0; s < 2; ++s)
            bfrag[c][s] = *(const v4i*)(tw + (c * 16 + ml) * 128 + s * 64 + quad * 16);

    __shared__ __align__(16) signed char lds_a[64 * 144];
    const float maxo = __uint_as_float(*(const unsigned*)(ws + WS_MAXO));
    const float iscale = maxo / 127.0f;
    const float4* x4 = (const float4*)(out + (size_t)in_row0 * 128);
#pragma unroll
    for (int it = 0; it < 8; ++it) {
        const int i = tid + it * 256;
        const int row = i >> 5, c4 = i & 31;
        const float4 v = x4[i];
        float a0 = fminf(fmaxf(rintf(v.x / iscale), -128.f), 127.f);
        float a1 = fminf(fmaxf(rintf(v.y / iscale), -128.f), 127.f);
        float a2 = fminf(fmaxf(rintf(v.z / iscale), -128.f), 127.f);
        float a3 = fminf(fmaxf(rintf(v.w / iscale), -128.f), 127.f);
        const int i0 = (int)a0, i1 = (int)a1, i2 = (int)a2, i3 = (int)a3;
        const int packed = (i0 & 0xff) | ((i1 & 0xff) << 8) | ((i2 & 0xff) << 16) | (i3 << 24);
        *(int*)(lds_a + row * 144 + c4 * 4) = packed;
    }
    __syncthreads();

    const v4i afrag0 = *(const v4i*)(lds_a + (wv * 16 + ml) * 144 + quad * 16);
    const v4i afrag1 = *(const v4i*)(lds_a + (wv * 16 + ml) * 144 + 64 + quad * 16);

    const float wsc = ((const float*)(ws + WS_WS))[3];
    const float scale = wsc * iscale;

#pragma unroll
    for (int c = 0; c < 8; ++c) {
        v4i acc = {0, 0, 0, 0};
        acc = __builtin_amdgcn_mfma_i32_16x16x64_i8(afrag0, bfrag[c][0], acc, 0, 0, 0);
        acc = __builtin_amdgcn_mfma_i32_16x16x64_i8(afrag1, bfrag[c][1], acc, 0, 0, 0);
        const int col = c * 16 + ml;
        const float bcol = ob[col];
#pragma unroll
        for (int r = 0; r < 4; ++r) {
            const int row = wv * 16 + quad * 4 + r;
            out[(size_t)(in_row0 + row) * 128 + col] = (float)acc[r] * scale + bcol;
        }
    }
}

__global__ void copy_newkv(const char* __restrict__ ws, float* __restrict__ out) {
    const int n = BB * NH * WINDOW * 16;  // 524288
    const float* kbuf = (const float*)(ws + WS_KBUF);
    const float* vbuf = (const float*)(ws + WS_VBUF);
    float* nk = out + (size_t)ROWS * EE;
    float* nv = nk + n;
    for (int i = blockIdx.x * blockDim.x + threadIdx.x; i < n; i += gridDim.x * blockDim.x) {
        const int d = i & 15, p = (i >> 4) & 127, h = (i >> 11) & 7, b = i >> 14;
        const size_t src = (size_t)(b * WINDOW + p) * 128 + h * 16 + d;
        nk[i] = kbuf[src];
        nv[i] = vbuf[src];
    }
}

extern "C" void kernel_launch(void* const* d_in, const int* in_sizes, int n_in,
                              void* d_out, int out_size, void* d_ws, size_t ws_size,
                              hipStream_t stream) {
    const float* x  = (const float*)d_in[0];
    const float* ck = (const float*)d_in[1];
    const float* cv = (const float*)d_in[2];
    const float* qw = (const float*)d_in[3];
    const float* qb = (const float*)d_in[4];
    const float* kw = (const float*)d_in[5];
    const float* kb = (const float*)d_in[6];
    const float* vw = (const float*)d_in[7];
    const float* vb = (const float*)d_in[8];
    const float* ow = (const float*)d_in[9];
    const float* ob = (const float*)d_in[10];
    char* ws = (char*)d_ws;
    float* out = (float*)d_out;

    prep_weights<<<4, 256, 0, stream>>>(qw, kw, vw, ow, ws);
    reduce_max_x<<<1024, 256, 0, stream>>>(x, ws);
    qkv_proj_mfma<<<1024 + 128, 256, 0, stream>>>(x, qb, kb, vb, ws);
    attention<<<dim3(SS / 256, NH, BB), 256, 0, stream>>>(ck, cv, ws, out);
    copy_newkv<<<512, 256, 0, stream>>>(ws, out);
    o_proj_mfma<<<1024, 256, 0, stream>>>(ob, ws, out);
}

// Round 3
// 242.392 us; speedup vs baseline: 1.5866x; 1.0553x over previous
//
#include <hip/hip_runtime.h>
#include <math.h>

#define BB 32
#define SS 2048
#define EE 128
#define NH 8
#define HDIM 16
#define CACHE_LEN 256
#define SINKS 4
#define WINDOW 128
#define KSEL (SINKS + WINDOW)   // 132
#define ROWS (BB * SS)          // 65536

typedef int v4i __attribute__((ext_vector_type(4)));

// workspace layout (bytes)
#define WS_MAXX 0                         // int bits of max|x| (nonneg float as int)
#define WS_MAXO 4                         // int bits of max|attn_out|
#define WS_WS   16                        // float[4] w_scales (q,k,v,o)
#define WS_W(i) (256 + (i) * 16384)       // ternary int8, row-major [o][e]
#define WS_QBUF (256 + 4 * 16384)         // q rows, head-major: [b][h][s][16] f32

// d_out layout: [0, ROWS*128) attn-out then final output (in-place o_proj);
// new_k at ROWS*128, new_v at ROWS*128 + 524288
#define NKV_N (BB * NH * WINDOW * HDIM)   // 524288

// ---- fused weight prep (blocks 0..3) + max|x| (blocks 4..515) -----------
__global__ void prep_and_max(const float* __restrict__ qw, const float* __restrict__ kw,
                             const float* __restrict__ vw, const float* __restrict__ ow,
                             const float* __restrict__ x, char* __restrict__ ws) {
    const int tid = threadIdx.x;
    if (blockIdx.x < 4) {
        const float* W[4] = {qw, kw, vw, ow};
        const int m = blockIdx.x;
        const float* w = W[m];
        __shared__ double red[256];
        double s = 0.0;
        for (int j = tid; j < 16384; j += 256) s += fabs((double)w[j]);
        red[tid] = s;
        __syncthreads();
        for (int st = 128; st > 0; st >>= 1) {
            if (tid < st) red[tid] += red[tid + st];
            __syncthreads();
        }
        const double wscale = red[0] / 16384.0;
        const double thr = 0.5 * wscale;
        if (tid == 0) ((float*)(ws + WS_WS))[m] = (float)wscale;
        signed char* tw = (signed char*)(ws + WS_W(m));
        for (int j = tid; j < 16384; j += 256) {
            const float wv = w[j];
            const double av = fabs((double)wv);
            tw[j] = (av > thr) ? (wv > 0.f ? (signed char)1 : (signed char)-1) : (signed char)0;
        }
    } else {
        __shared__ float red[256];
        float mx = 0.f;
        const int n4 = ROWS * EE / 4;
        const int nthreads = 512 * 256;
        for (int i = (blockIdx.x - 4) * 256 + tid; i < n4; i += nthreads) {
            const float4 v = ((const float4*)x)[i];
            mx = fmaxf(mx, fmaxf(fmaxf(fabsf(v.x), fabsf(v.y)), fmaxf(fabsf(v.z), fabsf(v.w))));
        }
        red[tid] = mx;
        __syncthreads();
        for (int st = 128; st > 0; st >>= 1) {
            if (tid < st) red[tid] = fmaxf(red[tid], red[tid + st]);
            __syncthreads();
        }
        // nonneg float bits as signed int: int-max == float-max; poison (0xAA..) is negative
        if (tid == 0) atomicMax((int*)(ws + WS_MAXX), __float_as_int(red[0]));
    }
}

// ---- int8 MFMA QKV projection -------------------------------------------
// blocks 0..1023: Q (all rows) -> QBUF head-major
// blocks 1024..1151: K,V (window rows only) -> new_k/new_v region of d_out
__global__ __launch_bounds__(256) void qkv_proj_mfma(const float* __restrict__ x,
                                                     const float* __restrict__ qb,
                                                     const float* __restrict__ kb,
                                                     const float* __restrict__ vb,
                                                     char* __restrict__ ws,
                                                     float* __restrict__ out) {
    const int bx = blockIdx.x;
    const int tid = threadIdx.x;
    int proj, in_row0, b_blk, s0;   // s0: seq offset (Q) or window offset (K/V)
    if (bx < 1024) {
        proj = 0; in_row0 = bx * 64; b_blk = bx >> 5; s0 = (bx * 64) & 2047;
    } else {
        int widx = bx - 1024;
        proj = 1 + (widx >> 6);
        widx &= 63;
        b_blk = widx >> 1;
        s0 = (widx & 1) * 64;
        in_row0 = b_blk * 2048 + (SS - WINDOW) + s0;
    }
    const float* bias = (proj == 0) ? qb : (proj == 1) ? kb : vb;
    const signed char* tw = (const signed char*)(ws + WS_W(proj));
    float* dst = (proj == 0) ? (float*)(ws + WS_QBUF)
               : (proj == 1) ? (out + (size_t)ROWS * EE)
                             : (out + (size_t)ROWS * EE + NKV_N);

    const int lane = tid & 63;
    const int wv = tid >> 6;
    const int ml = lane & 15;
    const int quad = lane >> 4;

    v4i bfrag[8][2];
#pragma unroll
    for (int c = 0; c < 8; ++c)
#pragma unroll
        for (int s = 0; s < 2; ++s)
            bfrag[c][s] = *(const v4i*)(tw + (c * 16 + ml) * 128 + s * 64 + quad * 16);

    __shared__ __align__(16) signed char lds_a[64 * 144];
    const float maxx = __int_as_float(*(const int*)(ws + WS_MAXX));
    const float iscale = maxx / 127.0f;
    const float4* x4 = (const float4*)(x + (size_t)in_row0 * 128);
#pragma unroll
    for (int it = 0; it < 8; ++it) {
        const int i = tid + it * 256;
        const int row = i >> 5, c4 = i & 31;
        const float4 v = x4[i];
        float a0 = fminf(fmaxf(rintf(v.x / iscale), -128.f), 127.f);
        float a1 = fminf(fmaxf(rintf(v.y / iscale), -128.f), 127.f);
        float a2 = fminf(fmaxf(rintf(v.z / iscale), -128.f), 127.f);
        float a3 = fminf(fmaxf(rintf(v.w / iscale), -128.f), 127.f);
        const int i0 = (int)a0, i1 = (int)a1, i2 = (int)a2, i3 = (int)a3;
        const int packed = (i0 & 0xff) | ((i1 & 0xff) << 8) | ((i2 & 0xff) << 16) | (i3 << 24);
        *(int*)(lds_a + row * 144 + c4 * 4) = packed;
    }
    __syncthreads();

    const v4i afrag0 = *(const v4i*)(lds_a + (wv * 16 + ml) * 144 + quad * 16);
    const v4i afrag1 = *(const v4i*)(lds_a + (wv * 16 + ml) * 144 + 64 + quad * 16);

    const float wsc = ((const float*)(ws + WS_WS))[proj];
    const float scale = wsc * iscale;

#pragma unroll
    for (int c = 0; c < 8; ++c) {
        v4i acc = {0, 0, 0, 0};
        acc = __builtin_amdgcn_mfma_i32_16x16x64_i8(afrag0, bfrag[c][0], acc, 0, 0, 0);
        acc = __builtin_amdgcn_mfma_i32_16x16x64_i8(afrag1, bfrag[c][1], acc, 0, 0, 0);
        const int col = c * 16 + ml;
        const int h = col >> 4, d = col & 15;
        const float bcol = bias[col];
        const int slen = (proj == 0) ? SS : WINDOW;
#pragma unroll
        for (int r = 0; r < 4; ++r) {
            const int srow = s0 + wv * 16 + quad * 4 + r;
            dst[((size_t)(b_blk * NH + h) * slen + srow) * 16 + d] = (float)acc[r] * scale + bcol;
        }
    }
}

// ---- attention: 4 queries per thread, chunked online softmax ------------
// K/V LDS reads amortized 4x; all lanes broadcast-read the same key.
__global__ __launch_bounds__(256, 2) void attention(const float* __restrict__ ck,
                                                    const float* __restrict__ cv,
                                                    char* __restrict__ ws,
                                                    float* __restrict__ out) {
    const int qt = blockIdx.x, h = blockIdx.y, b = blockIdx.z;
    __shared__ __align__(16) float ksh[KSEL * 16];
    __shared__ __align__(16) float vsh[KSEL * 16];
    __shared__ float red[256];
    const int tid = threadIdx.x;
    const float* nkbuf = out + (size_t)ROWS * EE;
    const float* nvbuf = nkbuf + NKV_N;
    for (int idx = tid; idx < KSEL * 16; idx += 256) {
        const int j = idx >> 4, d = idx & 15;
        float kv, vv;
        if (j < SINKS) {
            kv = ck[((size_t)(b * NH + h) * CACHE_LEN + j) * 16 + d];
            vv = cv[((size_t)(b * NH + h) * CACHE_LEN + j) * 16 + d];
        } else {
            kv = nkbuf[((size_t)(b * NH + h) * WINDOW + (j - SINKS)) * 16 + d];
            vv = nvbuf[((size_t)(b * NH + h) * WINDOW + (j - SINKS)) * 16 + d];
        }
        ksh[idx] = kv;
        vsh[idx] = vv;
    }
    __syncthreads();

    const int q0 = qt * 1024 + tid;
    const float* qbuf = (const float*)(ws + WS_QBUF) + (size_t)(b * NH + h) * SS * 16;

    float q[4][16], o[4][16], m[4], l[4];
    int jm[4];
#pragma unroll
    for (int u = 0; u < 4; ++u) {
        const int qi = q0 + u * 256;
        jm[u] = (qi < KSEL - 1) ? qi : (KSEL - 1);
        m[u] = -INFINITY;
        l[u] = 0.f;
#pragma unroll
        for (int i = 0; i < 4; ++i) {
            const float4 v = ((const float4*)(qbuf + (size_t)qi * 16))[i];
            // fold 1/sqrt(16)=0.25 into q (exact: power of two)
            q[u][i * 4 + 0] = v.x * 0.25f;
            q[u][i * 4 + 1] = v.y * 0.25f;
            q[u][i * 4 + 2] = v.z * 0.25f;
            q[u][i * 4 + 3] = v.w * 0.25f;
        }
#pragma unroll
        for (int d = 0; d < 16; ++d) o[u][d] = 0.f;
    }

#pragma unroll 1
    for (int ch = 0; ch < 12; ++ch) {   // 12 chunks x 11 keys = 132
        const int j0 = ch * 11;
        float sc[4][11];
#pragma unroll
        for (int i = 0; i < 11; ++i) {
            const int j = j0 + i;
            float kj[16];
#pragma unroll
            for (int z = 0; z < 4; ++z) {
                const float4 v = ((const float4*)(ksh + j * 16))[z];
                kj[z * 4 + 0] = v.x; kj[z * 4 + 1] = v.y;
                kj[z * 4 + 2] = v.z; kj[z * 4 + 3] = v.w;
            }
#pragma unroll
            for (int u = 0; u < 4; ++u) {
                float s = 0.f;
#pragma unroll
                for (int d = 0; d < 16; ++d) s = fmaf(q[u][d], kj[d], s);
                sc[u][i] = (j <= jm[u]) ? s : -INFINITY;
            }
        }
#pragma unroll
        for (int u = 0; u < 4; ++u) {
            float mc = sc[u][0];
#pragma unroll
            for (int i = 1; i < 11; ++i) mc = fmaxf(mc, sc[u][i]);
            const float mn = fmaxf(m[u], mc);
            const float cs = __expf(m[u] - mn);  // chunk 0: exp(-inf)=0
            l[u] *= cs;
#pragma unroll
            for (int d = 0; d < 16; ++d) o[u][d] *= cs;
            m[u] = mn;
        }
#pragma unroll
        for (int i = 0; i < 11; ++i) {
            const int j = j0 + i;
            float vj[16];
#pragma unroll
            for (int z = 0; z < 4; ++z) {
                const float4 v = ((const float4*)(vsh + j * 16))[z];
                vj[z * 4 + 0] = v.x; vj[z * 4 + 1] = v.y;
                vj[z * 4 + 2] = v.z; vj[z * 4 + 3] = v.w;
            }
#pragma unroll
            for (int u = 0; u < 4; ++u) {
                const float p = __expf(sc[u][i] - m[u]);
                l[u] += p;
#pragma unroll
                for (int d = 0; d < 16; ++d) o[u][d] = fmaf(p, vj[d], o[u][d]);
            }
        }
    }

    float tm = 0.f;
#pragma unroll
    for (int u = 0; u < 4; ++u) {
        const int qi = q0 + u * 256;
        const float inv = 1.0f / l[u];
        float* ao = out + (size_t)(b * SS + qi) * 128 + h * 16;
#pragma unroll
        for (int i = 0; i < 4; ++i) {
            float4 v;
            v.x = o[u][i * 4 + 0] * inv;
            v.y = o[u][i * 4 + 1] * inv;
            v.z = o[u][i * 4 + 2] * inv;
            v.w = o[u][i * 4 + 3] * inv;
            tm = fmaxf(tm, fmaxf(fmaxf(fabsf(v.x), fabsf(v.y)), fmaxf(fabsf(v.z), fabsf(v.w))));
            ((float4*)ao)[i] = v;
        }
    }
    red[tid] = tm;
    __syncthreads();
    for (int st = 128; st > 0; st >>= 1) {
        if (tid < st) red[tid] = fmaxf(red[tid], red[tid + st]);
        __syncthreads();
    }
    if (tid == 0) atomicMax((int*)(ws + WS_MAXO), __float_as_int(red[0]));
}

// ---- O projection, int8 MFMA, in-place on d_out -------------------------
__global__ __launch_bounds__(256) void o_proj_mfma(const float* __restrict__ ob,
                                                   char* __restrict__ ws,
                                                   float* __restrict__ out) {
    const int bx = blockIdx.x;
    const int tid = threadIdx.x;
    const int in_row0 = bx * 64;
    const signed char* tw = (const signed char*)(ws + WS_W(3));

    const int lane = tid & 63;
    const int wv = tid >> 6;
    const int ml = lane & 15;
    const int quad = lane >> 4;

    v4i bfrag[8][2];
#pragma unroll
    for (int c = 0; c < 8; ++c)
#pragma unroll
        for (int s = 0; s < 2; ++s)
            bfrag[c][s] = *(const v4i*)(tw + (c * 16 + ml) * 128 + s * 64 + quad * 16);

    __shared__ __align__(16) signed char lds_a[64 * 144];
    const float maxo = __int_as_float(*(const int*)(ws + WS_MAXO));
    const float iscale = maxo / 127.0f;
    const float4* x4 = (const float4*)(out + (size_t)in_row0 * 128);
#pragma unroll
    for (int it = 0; it < 8; ++it) {
        const int i = tid + it * 256;
        const int row = i >> 5, c4 = i & 31;
        const float4 v = x4[i];
        float a0 = fminf(fmaxf(rintf(v.x / iscale), -128.f), 127.f);
        float a1 = fminf(fmaxf(rintf(v.y / iscale), -128.f), 127.f);
        float a2 = fminf(fmaxf(rintf(v.z / iscale), -128.f), 127.f);
        float a3 = fminf(fmaxf(rintf(v.w / iscale), -128.f), 127.f);
        const int i0 = (int)a0, i1 = (int)a1, i2 = (int)a2, i3 = (int)a3;
        const int packed = (i0 & 0xff) | ((i1 & 0xff) << 8) | ((i2 & 0xff) << 16) | (i3 << 24);
        *(int*)(lds_a + row * 144 + c4 * 4) = packed;
    }
    __syncthreads();

    const v4i afrag0 = *(const v4i*)(lds_a + (wv * 16 + ml) * 144 + quad * 16);
    const v4i afrag1 = *(const v4i*)(lds_a + (wv * 16 + ml) * 144 + 64 + quad * 16);

    const float wsc = ((const float*)(ws + WS_WS))[3];
    const float scale = wsc * iscale;

#pragma unroll
    for (int c = 0; c < 8; ++c) {
        v4i acc = {0, 0, 0, 0};
        acc = __builtin_amdgcn_mfma_i32_16x16x64_i8(afrag0, bfrag[c][0], acc, 0, 0, 0);
        acc = __builtin_amdgcn_mfma_i32_16x16x64_i8(afrag1, bfrag[c][1], acc, 0, 0, 0);
        const int col = c * 16 + ml;
        const float bcol = ob[col];
#pragma unroll
        for (int r = 0; r < 4; ++r) {
            const int row = wv * 16 + quad * 4 + r;
            out[(size_t)(in_row0 + row) * 128 + col] = (float)acc[r] * scale + bcol;
        }
    }
}

extern "C" void kernel_launch(void* const* d_in, const int* in_sizes, int n_in,
                              void* d_out, int out_size, void* d_ws, size_t ws_size,
                              hipStream_t stream) {
    const float* x  = (const float*)d_in[0];
    const float* ck = (const float*)d_in[1];
    const float* cv = (const float*)d_in[2];
    const float* qw = (const float*)d_in[3];
    const float* qb = (const float*)d_in[4];
    const float* kw = (const float*)d_in[5];
    const float* kb = (const float*)d_in[6];
    const float* vw = (const float*)d_in[7];
    const float* vb = (const float*)d_in[8];
    const float* ow = (const float*)d_in[9];
    const float* ob = (const float*)d_in[10];
    char* ws = (char*)d_ws;
    float* out = (float*)d_out;

    prep_and_max<<<4 + 512, 256, 0, stream>>>(qw, kw, vw, ow, x, ws);
    qkv_proj_mfma<<<1024 + 128, 256, 0, stream>>>(x, qb, kb, vb, ws, out);
    attention<<<dim3(2, NH, BB), 256, 0, stream>>>(ck, cv, ws, out);
    o_proj_mfma<<<1024, 256, 0, stream>>>(ob, ws, out);
}